// Round 1
// 1058.039 us; speedup vs baseline: 1.3829x; 1.3829x over previous
//
#include <hip/hip_runtime.h>
#include <hip/hip_bf16.h>

typedef __hip_bfloat16 bf16;
typedef __attribute__((ext_vector_type(8))) short short8;
typedef __attribute__((ext_vector_type(4))) float floatx4;

#define K_DIM 4096
#define N_DIM 4096
#define M_DIM 16384
#define RANK  64

// ---------------------------------------------------------------------------
// fp32 -> bf16 bulk convert (x: [16384,4096]). 8 elements/thread.
// ---------------------------------------------------------------------------
__global__ __launch_bounds__(256) void cvt_x_kernel(
    const float4* __restrict__ in, short8* __restrict__ out)
{
    const int i = blockIdx.x * 256 + threadIdx.x;
    const float4 a = in[2 * i];
    const float4 b = in[2 * i + 1];
    bf16 t[8];
    t[0] = __float2bfloat16(a.x); t[1] = __float2bfloat16(a.y);
    t[2] = __float2bfloat16(a.z); t[3] = __float2bfloat16(a.w);
    t[4] = __float2bfloat16(b.x); t[5] = __float2bfloat16(b.y);
    t[6] = __float2bfloat16(b.z); t[7] = __float2bfloat16(b.w);
    out[i] = *(const short8*)t;
}

// ---------------------------------------------------------------------------
// W_eff[n,k] = W[n,k] + sum_r p[n,r]*lam[r]*q[r,k] - sum_r bp[n,r]*blam[r]*bq[r,k]
// ---------------------------------------------------------------------------
__global__ __launch_bounds__(256) void prep_weff_kernel(
    const float* __restrict__ W, const float* __restrict__ q,
    const float* __restrict__ p, const float* __restrict__ lam,
    const float* __restrict__ bq, const float* __restrict__ bp,
    const float* __restrict__ blam, bf16* __restrict__ Weff)
{
    const int k  = blockIdx.x * 256 + threadIdx.x;
    const int n0 = blockIdx.y * 8;
    float acc[8];
#pragma unroll
    for (int i = 0; i < 8; ++i) acc[i] = 0.0f;

    for (int r = 0; r < RANK; ++r) {
        const float qlv  = lam[r]  * q [r * K_DIM + k];
        const float bqlv = blam[r] * bq[r * K_DIM + k];
#pragma unroll
        for (int i = 0; i < 8; ++i) {
            acc[i] += p [(n0 + i) * RANK + r] * qlv;
            acc[i] -= bp[(n0 + i) * RANK + r] * bqlv;
        }
    }
#pragma unroll
    for (int i = 0; i < 8; ++i) {
        const size_t idx = (size_t)(n0 + i) * K_DIM + k;
        Weff[idx] = __float2bfloat16(W[idx] + acc[i]);
    }
}

// ---------------------------------------------------------------------------
// 256x256 8-phase GEMM: C[M,N] = A[M,K] * B[N,K]^T, A/B bf16, C fp32.
// 512 thr = 8 waves (2M x 4N), per-wave 128x64 out (acc[8][4]), BK=64.
// LDS 128 KiB = 2 K-tile dbuf x (A 32K + B 32K); half-tile = 128 rows x 64 k.
// T1 XCD swizzle, T2 XOR-swizzle ((row&7)<<4), T3+T4 counted vmcnt(4) only at
// phases 4/8, T5 setprio around MFMA clusters.
//
// Stage-slot safety (half staged in phase p => last read in phase < p,
// reads drained by that phase's lgkmcnt(0), stage issued after its barrier):
//   buf0.A (tile t):  read ph1-2            -> A(t+2) staged ph3,ph4
//   buf0.B (tile t):  read ph1,ph3          -> B(t+2) staged ph5,ph6
//   buf1.A (tile t+1):read ph5-6            -> A(t+3) staged ph7,ph8
//   buf1.B (tile t+1):read ph5,ph7          -> B(t+1) staged ph1,ph2 (prev dead)
// vmcnt(4) @ph4 retires A0,A1,B0,B1(t+1) (oldest 8 of 12); @ph8 retires t+2.
// Last iteration: prefetch targets clamp to tile 63 (harmless rewrite of dead
// halves) so vmcnt accounting is identical every iteration.
// ---------------------------------------------------------------------------
__device__ __forceinline__ void stage2(const bf16* g0, const bf16* g1, char* d)
{
    __builtin_amdgcn_global_load_lds(
        (const __attribute__((address_space(1))) void*)g0,
        (__attribute__((address_space(3))) void*)d, 16, 0, 0);
    __builtin_amdgcn_global_load_lds(
        (const __attribute__((address_space(1))) void*)g1,
        (__attribute__((address_space(3))) void*)(d + 8192), 16, 0, 0);
}

__device__ __forceinline__ void lda4(short8 (&dst)[4], const char* base,
                                     int off, int kb)
{
#pragma unroll
    for (int fr = 0; fr < 4; ++fr)
        dst[fr] = *(const short8*)(base + off + fr * 2048 + kb);
}

__device__ __forceinline__ void ldb4(short8 (&dst)[4], const char* base,
                                     int off, int kb)
{
#pragma unroll
    for (int fc = 0; fc < 4; ++fc)
        dst[fc] = *(const short8*)(base + off + fc * 2048 + kb);
}

__device__ __forceinline__ void mma16(floatx4 (&acc)[8][4], int rbase,
                                      const short8 (&av)[4], const short8 (&bv)[4])
{
#pragma unroll
    for (int fr = 0; fr < 4; ++fr)
#pragma unroll
        for (int fc = 0; fc < 4; ++fc)
            acc[rbase + fr][fc] = __builtin_amdgcn_mfma_f32_16x16x32_bf16(
                av[fr], bv[fc], acc[rbase + fr][fc], 0, 0, 0);
}

#define PHASE_TAIL(R0_, AV_, BV_) do {                         \
    __builtin_amdgcn_s_barrier();                              \
    asm volatile("s_waitcnt lgkmcnt(0)" ::: "memory");         \
    __builtin_amdgcn_s_setprio(1);                             \
    mma16(acc, R0_, AV_, BV_);                                 \
    __builtin_amdgcn_s_setprio(0);                             \
    __builtin_amdgcn_s_barrier();                              \
} while (0)

#define PHASE_TAIL_VM(R0_, AV_, BV_) do {                      \
    __builtin_amdgcn_s_barrier();                              \
    asm volatile("s_waitcnt lgkmcnt(0)" ::: "memory");         \
    __builtin_amdgcn_s_setprio(1);                             \
    mma16(acc, R0_, AV_, BV_);                                 \
    __builtin_amdgcn_s_setprio(0);                             \
    asm volatile("s_waitcnt vmcnt(4)" ::: "memory");           \
    __builtin_amdgcn_s_barrier();                              \
} while (0)

__global__ __launch_bounds__(512, 2) void gemm256_8ph_kernel(
    const bf16* __restrict__ A, const bf16* __restrict__ B, float* __restrict__ C)
{
    __shared__ __align__(16) char lds_buf[131072];

    const int tid  = threadIdx.x;
    const int lane = tid & 63;
    const int wave = tid >> 6;   // 0..7
    const int wm   = wave >> 2;  // 0..1
    const int wn   = wave & 3;   // 0..3

    // T1: XCD-aware bijective swizzle (1024 wgs, 8 XCDs, 128 contiguous each)
    const int bid = blockIdx.x;
    const int wg  = (bid & 7) * 128 + (bid >> 3);
    const int bx  = wg & 15;     // 4096/256 N-tiles
    const int by  = wg >> 4;     // 16384/256 M-tiles
    const int tm  = by * 256;
    const int tn  = bx * 256;

    // ---- staging source pointers: inverse-swizzled column so that linear
    // LDS dest + swizzled read reconstructs row-major (rule #21) ----
    const int r0  = tid >> 3;                          // 0..63
    const int csw = (((tid & 7) ^ (r0 & 7)) << 3);     // element col 0..56
    const bf16* gA0 = A + (size_t)(tm +       r0) * K_DIM + csw;
    const bf16* gA1 = A + (size_t)(tm +  64 + r0) * K_DIM + csw;
    const bf16* gA2 = A + (size_t)(tm + 128 + r0) * K_DIM + csw;
    const bf16* gA3 = A + (size_t)(tm + 192 + r0) * K_DIM + csw;
    const bf16* gB0 = B + (size_t)(tn +       r0) * K_DIM + csw;
    const bf16* gB1 = B + (size_t)(tn +  64 + r0) * K_DIM + csw;
    const bf16* gB2 = B + (size_t)(tn + 128 + r0) * K_DIM + csw;
    const bf16* gB3 = B + (size_t)(tn + 192 + r0) * K_DIM + csw;

    char* ldsA = (char*)lds_buf;          // [buf][256][64] bf16, +65536/buf
    char* ldsB = ldsA + 32768;
    const int wb = wave * 1024;           // wave-uniform stage base

    // ---- ds-read lane bases (T2 swizzle: byte ^= ((row&7)<<4)) ----
    const int l15 = lane & 15;
    const int kb0 = ((lane >> 4) << 4) ^ ((lane & 7) << 4);  // k-sub 0
    const int kb1 = kb0 ^ 64;                                // k-sub 1
    const char* aB = ldsA + (wm * 128 + l15) * 128;
    const char* bB = ldsB + (wn * 64  + l15) * 128;

    floatx4 acc[8][4];
#pragma unroll
    for (int p = 0; p < 8; ++p)
#pragma unroll
        for (int q = 0; q < 4; ++q) acc[p][q] = (floatx4){0.f, 0.f, 0.f, 0.f};

    short8 a0k0[4], a0k1[4], a1k0[4], a1k1[4], bk0[4], bk1[4];

    // ---- prologue: tile0 (A0,A1,B0,B1)->buf0; tile1 (A0,A1)->buf1 ----
    stage2(gA0, gA1, ldsA + wb);
    stage2(gA2, gA3, ldsA + 16384 + wb);
    stage2(gB0, gB1, ldsB + wb);
    stage2(gB2, gB3, ldsB + 16384 + wb);
    stage2(gA0 + 64, gA1 + 64, ldsA + 65536 + wb);
    stage2(gA2 + 64, gA3 + 64, ldsA + 65536 + 16384 + wb);
    asm volatile("s_waitcnt vmcnt(4)" ::: "memory");  // tile0 landed; t1 A in flight
    __builtin_amdgcn_s_barrier();

#pragma unroll 1
    for (int i = 0; i < 32; ++i) {
        const int kt1 = (2 * i + 1) * 64;
        const int kt2 = ((2 * i + 2 < 64) ? (2 * i + 2) : 63) * 64;
        const int kt3 = ((2 * i + 3 < 64) ? (2 * i + 3) : 63) * 64;

        // ph1: buf0 read A mh0 (k0,k1) + B k0  |  stage B0(t+1)->buf1
        lda4(a0k0, aB, 0, kb0);
        lda4(a0k1, aB, 0, kb1);
        ldb4(bk0, bB, 0, kb0);
        stage2(gB0 + kt1, gB1 + kt1, ldsB + 65536 + wb);
        PHASE_TAIL(0, a0k0, bk0);

        // ph2: buf0 read A mh1 (k0,k1)         |  stage B1(t+1)->buf1
        lda4(a1k0, aB, 8192, kb0);
        lda4(a1k1, aB, 8192, kb1);
        stage2(gB2 + kt1, gB3 + kt1, ldsB + 65536 + 16384 + wb);
        PHASE_TAIL(4, a1k0, bk0);

        // ph3: buf0 read B k1                  |  stage A0(t+2)->buf0 (A dead)
        ldb4(bk1, bB, 0, kb1);
        stage2(gA0 + kt2, gA1 + kt2, ldsA + wb);
        PHASE_TAIL(0, a0k1, bk1);

        // ph4:                                 |  stage A1(t+2)->buf0 ; vmcnt(4)
        stage2(gA2 + kt2, gA3 + kt2, ldsA + 16384 + wb);
        PHASE_TAIL_VM(4, a1k1, bk1);            // retires all of tile t+1

        // ph5: buf1 read A mh0 (k0,k1) + B k0  |  stage B0(t+2)->buf0 (B dead)
        lda4(a0k0, aB, 65536, kb0);
        lda4(a0k1, aB, 65536, kb1);
        ldb4(bk0, bB, 65536, kb0);
        stage2(gB0 + kt2, gB1 + kt2, ldsB + wb);
        PHASE_TAIL(0, a0k0, bk0);

        // ph6: buf1 read A mh1 (k0,k1)         |  stage B1(t+2)->buf0
        lda4(a1k0, aB, 65536 + 8192, kb0);
        lda4(a1k1, aB, 65536 + 8192, kb1);
        stage2(gB2 + kt2, gB3 + kt2, ldsB + 16384 + wb);
        PHASE_TAIL(4, a1k0, bk0);

        // ph7: buf1 read B k1                  |  stage A0(t+3)->buf1 (A dead)
        ldb4(bk1, bB, 65536, kb1);
        stage2(gA0 + kt3, gA1 + kt3, ldsA + 65536 + wb);
        PHASE_TAIL(0, a0k1, bk1);

        // ph8:                                 |  stage A1(t+3)->buf1 ; vmcnt(4)
        stage2(gA2 + kt3, gA3 + kt3, ldsA + 65536 + 16384 + wb);
        PHASE_TAIL_VM(4, a1k1, bk1);            // retires all of tile t+2
    }

    // epilogue: C/D layout col=lane&15, row=(lane>>4)*4+reg (verified m89/m91)
    const int row0 = tm + wm * 128 + (lane >> 4) * 4;
    const int col0 = tn + wn * 64 + l15;
#pragma unroll
    for (int mf = 0; mf < 8; ++mf)
#pragma unroll
        for (int fc = 0; fc < 4; ++fc)
#pragma unroll
            for (int rr = 0; rr < 4; ++rr)
                C[(size_t)(row0 + mf * 16 + rr) * N_DIM + (col0 + fc * 16)] =
                    acc[mf][fc][rr];
}

extern "C" void kernel_launch(void* const* d_in, const int* in_sizes, int n_in,
                              void* d_out, int out_size, void* d_ws, size_t ws_size,
                              hipStream_t stream)
{
    const float* x    = (const float*)d_in[0];  // [4,4096,4096] fp32
    const float* Worg = (const float*)d_in[1];  // [4096,4096]
    const float* qw   = (const float*)d_in[2];  // [64,4096]
    const float* pw   = (const float*)d_in[3];  // [4096,64]
    const float* lam  = (const float*)d_in[4];  // [64]
    const float* bqw  = (const float*)d_in[5];
    const float* bpw  = (const float*)d_in[6];
    const float* blam = (const float*)d_in[7];
    float* out = (float*)d_out;                 // [16384,4096] fp32

    // ws layout: [x_bf16: 134217728 B][Weff: 33554432 B]
    bf16* x_bf = (bf16*)d_ws;
    bf16* Weff = (bf16*)((char*)d_ws + (size_t)M_DIM * K_DIM * 2);

    cvt_x_kernel<<<dim3((M_DIM * K_DIM) / (8 * 256)), 256, 0, stream>>>(
        (const float4*)x, (short8*)x_bf);

    prep_weff_kernel<<<dim3(K_DIM / 256, N_DIM / 8), 256, 0, stream>>>(
        Worg, qw, pw, lam, bqw, bpw, blam, Weff);

    // grid: (16384/256) * (4096/256) = 64*16 = 1024 blocks, 512 threads
    gemm256_8ph_kernel<<<dim3(1024), 512, 0, stream>>>(x_bf, Weff, out);
}

// Round 2
// 1052.991 us; speedup vs baseline: 1.3895x; 1.0048x over previous
//
#include <hip/hip_runtime.h>
#include <hip/hip_bf16.h>

typedef __hip_bfloat16 bf16;
typedef __attribute__((ext_vector_type(8))) short short8;
typedef __attribute__((ext_vector_type(4))) float floatx4;

#define K_DIM 4096
#define N_DIM 4096
#define M_DIM 16384
#define RANK  64

// ---------------------------------------------------------------------------
// fp32 -> bf16 bulk convert (x: [16384,4096]). 8 elements/thread.
// ---------------------------------------------------------------------------
__global__ __launch_bounds__(256) void cvt_x_kernel(
    const float4* __restrict__ in, short8* __restrict__ out)
{
    const int i = blockIdx.x * 256 + threadIdx.x;
    const float4 a = in[2 * i];
    const float4 b = in[2 * i + 1];
    bf16 t[8];
    t[0] = __float2bfloat16(a.x); t[1] = __float2bfloat16(a.y);
    t[2] = __float2bfloat16(a.z); t[3] = __float2bfloat16(a.w);
    t[4] = __float2bfloat16(b.x); t[5] = __float2bfloat16(b.y);
    t[6] = __float2bfloat16(b.z); t[7] = __float2bfloat16(b.w);
    out[i] = *(const short8*)t;
}

// ---------------------------------------------------------------------------
// W_eff[n,k] = W[n,k] + sum_r p[n,r]*lam[r]*q[r,k] - sum_r bp[n,r]*blam[r]*bq[r,k]
// ---------------------------------------------------------------------------
__global__ __launch_bounds__(256) void prep_weff_kernel(
    const float* __restrict__ W, const float* __restrict__ q,
    const float* __restrict__ p, const float* __restrict__ lam,
    const float* __restrict__ bq, const float* __restrict__ bp,
    const float* __restrict__ blam, bf16* __restrict__ Weff)
{
    const int k  = blockIdx.x * 256 + threadIdx.x;
    const int n0 = blockIdx.y * 8;
    float acc[8];
#pragma unroll
    for (int i = 0; i < 8; ++i) acc[i] = 0.0f;

    for (int r = 0; r < RANK; ++r) {
        const float qlv  = lam[r]  * q [r * K_DIM + k];
        const float bqlv = blam[r] * bq[r * K_DIM + k];
#pragma unroll
        for (int i = 0; i < 8; ++i) {
            acc[i] += p [(n0 + i) * RANK + r] * qlv;
            acc[i] -= bp[(n0 + i) * RANK + r] * bqlv;
        }
    }
#pragma unroll
    for (int i = 0; i < 8; ++i) {
        const size_t idx = (size_t)(n0 + i) * K_DIM + k;
        Weff[idx] = __float2bfloat16(W[idx] + acc[i]);
    }
}

// ---------------------------------------------------------------------------
// 256x256 8-phase GEMM: C[M,N] = A[M,K] * B[N,K]^T, A/B bf16, C fp32.
// 512 thr = 8 waves (2M x 4N), per-wave 128x64 out (acc[8][4]), BK=64.
// LDS 160 KiB: A 2-buf (2x32K) + B 3-buf (3x32K).  B triple-buffering
// lengthens every stage->first-read distance to >=5 phases, so both vmcnt(8)
// waits retire loads issued 7-10 phases (~1500+ cyc) earlier -> no stall.
//
// Steady-state schedule for iter i (tiles t=2i, t+1):
//   reads:  ph1-4 tile t   (A buf0, B slot b0)
//           ph5-8 tile t+1 (A buf1, B slot b1)
//   stages: ph1-2 B(t+2)->b2   ph3-4 A(t+2)->buf0
//           ph5-6 B(t+3)->b0   ph7-8 A(t+3)->buf1
//   rotation: (b0,b1,b2) <- (b2,b0,b1)
// WAR: every buffer re-staged >=2 phases after its reads retired (phase-tail
// lgkmcnt + barrier), and the LDS write lands at global-data RETURN time
// (several hundred cycles after issue).
// vmcnt accounting (per-thread loads; stage2 = 2): 16 in flight at ph4/ph8;
// vmcnt(8) drains exactly the 8 oldest = the tile needed next half-iter.
// Counted lgkmcnt: ph1/5 issue 12 b128 reads, MFMA needs oldest 8 -> lgkm(4);
// ph2/6 issue 8, need oldest 4 (+already-landed) -> lgkm(4); ph3/7 -> 0.
// Last iteration: prefetch tile indices clamp to 63 (rewrite of dead halves),
// so vmcnt accounting is identical every iteration.
// ---------------------------------------------------------------------------
__device__ __forceinline__ void stage2(const bf16* g0, const bf16* g1, char* d)
{
    __builtin_amdgcn_global_load_lds(
        (const __attribute__((address_space(1))) void*)g0,
        (__attribute__((address_space(3))) void*)d, 16, 0, 0);
    __builtin_amdgcn_global_load_lds(
        (const __attribute__((address_space(1))) void*)g1,
        (__attribute__((address_space(3))) void*)(d + 8192), 16, 0, 0);
}

__device__ __forceinline__ void lda4(short8 (&dst)[4], const char* base,
                                     int off, int kb)
{
#pragma unroll
    for (int fr = 0; fr < 4; ++fr)
        dst[fr] = *(const short8*)(base + off + fr * 2048 + kb);
}

__device__ __forceinline__ void ldb4(short8 (&dst)[4], const char* base,
                                     int off, int kb)
{
#pragma unroll
    for (int fc = 0; fc < 4; ++fc)
        dst[fc] = *(const short8*)(base + off + fc * 2048 + kb);
}

__device__ __forceinline__ void mma16(floatx4 (&acc)[8][4], int rbase,
                                      const short8 (&av)[4], const short8 (&bv)[4])
{
#pragma unroll
    for (int fr = 0; fr < 4; ++fr)
#pragma unroll
        for (int fc = 0; fc < 4; ++fc)
            acc[rbase + fr][fc] = __builtin_amdgcn_mfma_f32_16x16x32_bf16(
                av[fr], bv[fc], acc[rbase + fr][fc], 0, 0, 0);
}

#define PHASE_TAIL(LG_, R0_, AV_, BV_) do {                    \
    __builtin_amdgcn_s_barrier();                              \
    asm volatile("s_waitcnt lgkmcnt(" #LG_ ")" ::: "memory");  \
    __builtin_amdgcn_s_setprio(1);                             \
    mma16(acc, R0_, AV_, BV_);                                 \
    __builtin_amdgcn_s_setprio(0);                             \
    __builtin_amdgcn_s_barrier();                              \
} while (0)

#define PHASE_TAIL_VM(R0_, AV_, BV_) do {                      \
    __builtin_amdgcn_s_barrier();                              \
    asm volatile("s_waitcnt lgkmcnt(0)" ::: "memory");         \
    __builtin_amdgcn_s_setprio(1);                             \
    mma16(acc, R0_, AV_, BV_);                                 \
    __builtin_amdgcn_s_setprio(0);                             \
    asm volatile("s_waitcnt vmcnt(8)" ::: "memory");           \
    __builtin_amdgcn_s_barrier();                              \
} while (0)

__global__ __launch_bounds__(512, 2) void gemm256_8ph_kernel(
    const bf16* __restrict__ A, const bf16* __restrict__ B, float* __restrict__ C)
{
    __shared__ __align__(16) char lds_buf[163840];

    const int tid  = threadIdx.x;
    const int lane = tid & 63;
    const int wave = tid >> 6;   // 0..7
    const int wm   = wave >> 2;  // 0..1
    const int wn   = wave & 3;   // 0..3

    // T1: XCD-aware bijective swizzle (1024 wgs, 8 XCDs, 128 contiguous each)
    const int bid = blockIdx.x;
    const int wg  = (bid & 7) * 128 + (bid >> 3);
    const int bx  = wg & 15;     // 4096/256 N-tiles
    const int by  = wg >> 4;     // 16384/256 M-tiles
    const int tm  = by * 256;
    const int tn  = bx * 256;

    // staging source: inverse-swizzled column (rule #21: linear LDS dest +
    // swizzled read require the same involution pre-applied to the source)
    const int r0  = tid >> 3;                          // 0..63
    const int csw = (((tid & 7) ^ (r0 & 7)) << 3);     // element col 0..56
    const bf16* gA0 = A + (size_t)(tm +       r0) * K_DIM + csw;
    const bf16* gA1 = A + (size_t)(tm +  64 + r0) * K_DIM + csw;
    const bf16* gA2 = A + (size_t)(tm + 128 + r0) * K_DIM + csw;
    const bf16* gA3 = A + (size_t)(tm + 192 + r0) * K_DIM + csw;
    const bf16* gB0 = B + (size_t)(tn +       r0) * K_DIM + csw;
    const bf16* gB1 = B + (size_t)(tn +  64 + r0) * K_DIM + csw;
    const bf16* gB2 = B + (size_t)(tn + 128 + r0) * K_DIM + csw;
    const bf16* gB3 = B + (size_t)(tn + 192 + r0) * K_DIM + csw;

    char* ldsA = (char*)lds_buf;          // A: 2 x 32768  ([128][64]bf16 x2 halves)
    char* ldsB = ldsA + 65536;            // B: 3 x 32768 rotating
    const int wb = wave * 1024;           // wave-uniform stage base

    // ds-read lane bases (T2 swizzle: byte ^= ((row&7)<<4))
    const int l15 = lane & 15;
    const int kb0 = ((lane >> 4) << 4) ^ ((lane & 7) << 4);  // k-sub 0
    const int kb1 = kb0 ^ 64;                                // k-sub 1
    const char* aB = ldsA + (wm * 128 + l15) * 128;
    const char* bB = ldsB + (wn * 64  + l15) * 128;

    floatx4 acc[8][4];
#pragma unroll
    for (int p = 0; p < 8; ++p)
#pragma unroll
        for (int q = 0; q < 4; ++q) acc[p][q] = (floatx4){0.f, 0.f, 0.f, 0.f};

    short8 a0k0[4], a0k1[4], a1k0[4], a1k1[4], bk0[4], bk1[4];

    // ---- prologue: A(0)->buf0, A(1)->buf1, B(0)->slot0, B(1)->slot1 ----
    stage2(gA0, gA1, ldsA + wb);
    stage2(gA2, gA3, ldsA + 16384 + wb);
    stage2(gA0 + 64, gA1 + 64, ldsA + 32768 + wb);
    stage2(gA2 + 64, gA3 + 64, ldsA + 32768 + 16384 + wb);
    stage2(gB0, gB1, ldsB + wb);
    stage2(gB2, gB3, ldsB + 16384 + wb);
    stage2(gB0 + 64, gB1 + 64, ldsB + 32768 + wb);
    stage2(gB2 + 64, gB3 + 64, ldsB + 32768 + 16384 + wb);
    asm volatile("s_waitcnt vmcnt(0)" ::: "memory");
    __builtin_amdgcn_s_barrier();

    int bO0 = 0, bO1 = 32768, bO2 = 65536;  // B slots of tiles t, t+1, (free)

#pragma unroll 1
    for (int i = 0; i < 32; ++i) {
        const int kt2 = ((2 * i + 2 < 64) ? (2 * i + 2) : 63) * 64;
        const int kt3 = ((2 * i + 3 < 64) ? (2 * i + 3) : 63) * 64;

        // ph1: read A(t) mh0 + B(t) k0 (oldest), A(t) mh0 k1 | stage B(t+2)->b2
        lda4(a0k0, aB, 0, kb0);
        ldb4(bk0, bB, bO0, kb0);
        lda4(a0k1, aB, 0, kb1);
        stage2(gB0 + kt2, gB1 + kt2, ldsB + bO2 + wb);
        PHASE_TAIL(4, 0, a0k0, bk0);

        // ph2: read A(t) mh1 (k0 oldest, k1)                | stage B(t+2)->b2
        lda4(a1k0, aB, 8192, kb0);
        lda4(a1k1, aB, 8192, kb1);
        stage2(gB2 + kt2, gB3 + kt2, ldsB + bO2 + 16384 + wb);
        PHASE_TAIL(4, 4, a1k0, bk0);

        // ph3: read B(t) k1                                 | stage A(t+2)->buf0
        ldb4(bk1, bB, bO0, kb1);
        stage2(gA0 + kt2, gA1 + kt2, ldsA + wb);
        PHASE_TAIL(0, 0, a0k1, bk1);

        // ph4:                                              | stage A(t+2)->buf0
        stage2(gA2 + kt2, gA3 + kt2, ldsA + 16384 + wb);
        PHASE_TAIL_VM(4, a1k1, bk1);   // vmcnt(8): drains A(t+1),B(t+1)

        // ph5: read A(t+1) mh0 + B(t+1) k0, A(t+1) mh0 k1   | stage B(t+3)->b0
        lda4(a0k0, aB, 32768, kb0);
        ldb4(bk0, bB, bO1, kb0);
        lda4(a0k1, aB, 32768, kb1);
        stage2(gB0 + kt3, gB1 + kt3, ldsB + bO0 + wb);
        PHASE_TAIL(4, 0, a0k0, bk0);

        // ph6: read A(t+1) mh1                              | stage B(t+3)->b0
        lda4(a1k0, aB, 32768 + 8192, kb0);
        lda4(a1k1, aB, 32768 + 8192, kb1);
        stage2(gB2 + kt3, gB3 + kt3, ldsB + bO0 + 16384 + wb);
        PHASE_TAIL(4, 4, a1k0, bk0);

        // ph7: read B(t+1) k1                               | stage A(t+3)->buf1
        ldb4(bk1, bB, bO1, kb1);
        stage2(gA0 + kt3, gA1 + kt3, ldsA + 32768 + wb);
        PHASE_TAIL(0, 0, a0k1, bk1);

        // ph8:                                              | stage A(t+3)->buf1
        stage2(gA2 + kt3, gA3 + kt3, ldsA + 32768 + 16384 + wb);
        PHASE_TAIL_VM(4, a1k1, bk1);   // vmcnt(8): drains A(t+2),B(t+2)

        // rotate B slots: next iter reads (t+2)@b2, (t+3)@b0; free = b1
        const int tmp = bO2; bO2 = bO1; bO1 = bO0; bO0 = tmp;
    }

    // epilogue: C/D layout col=lane&15, row=(lane>>4)*4+reg (verified m89/m91)
    const int row0 = tm + wm * 128 + (lane >> 4) * 4;
    const int col0 = tn + wn * 64 + l15;
#pragma unroll
    for (int mf = 0; mf < 8; ++mf)
#pragma unroll
        for (int fc = 0; fc < 4; ++fc)
#pragma unroll
            for (int rr = 0; rr < 4; ++rr)
                C[(size_t)(row0 + mf * 16 + rr) * N_DIM + (col0 + fc * 16)] =
                    acc[mf][fc][rr];
}

extern "C" void kernel_launch(void* const* d_in, const int* in_sizes, int n_in,
                              void* d_out, int out_size, void* d_ws, size_t ws_size,
                              hipStream_t stream)
{
    const float* x    = (const float*)d_in[0];  // [4,4096,4096] fp32
    const float* Worg = (const float*)d_in[1];  // [4096,4096]
    const float* qw   = (const float*)d_in[2];  // [64,4096]
    const float* pw   = (const float*)d_in[3];  // [4096,64]
    const float* lam  = (const float*)d_in[4];  // [64]
    const float* bqw  = (const float*)d_in[5];
    const float* bpw  = (const float*)d_in[6];
    const float* blam = (const float*)d_in[7];
    float* out = (float*)d_out;                 // [16384,4096] fp32

    // ws layout: [x_bf16: 134217728 B][Weff: 33554432 B]
    bf16* x_bf = (bf16*)d_ws;
    bf16* Weff = (bf16*)((char*)d_ws + (size_t)M_DIM * K_DIM * 2);

    cvt_x_kernel<<<dim3((M_DIM * K_DIM) / (8 * 256)), 256, 0, stream>>>(
        (const float4*)x, (short8*)x_bf);

    prep_weff_kernel<<<dim3(K_DIM / 256, N_DIM / 8), 256, 0, stream>>>(
        Worg, qw, pw, lam, bqw, bpw, blam, Weff);

    // grid: (16384/256) * (4096/256) = 64*16 = 1024 blocks, 512 threads
    gemm256_8ph_kernel<<<dim3(1024), 512, 0, stream>>>(x_bf, Weff, out);
}